// Round 1
// baseline (355.909 us; speedup 1.0000x reference)
//
#include <hip/hip_runtime.h>
#include <hip/hip_bf16.h>
#include <hip/hip_fp16.h>
#include <hip/hip_cooperative_groups.h>

namespace cg = cooperative_groups;

#define HW      262144   // 512*512 spatial positions
#define NCH     128      // channels (GEMM K)
#define NCLS    128      // classes  (GEMM N)
#define KROWS   131072   // gathered rows
#define NTILE   4096     // HW / 64
#define CAP     192      // entries per tile bucket (Poisson mean 32; P(>192) ~ 0)

typedef short  bf16x8 __attribute__((ext_vector_type(8)));
typedef float  f32x4  __attribute__((ext_vector_type(4)));

__device__ inline ushort f2bf(float f) {
    union { float f; unsigned u; } v; v.f = f;
    unsigned u = v.u;
    return (ushort)((u + 0x7FFFu + ((u >> 16) & 1u)) >> 16);   // RNE
}

// One persistent cooperative kernel:
//   phase 0: per-block W fp32->bf16 fragments into LDS; zero cnt; prefetch tile 0
//   grid.sync
//   phase 1: csr bucketing (k -> source tile), device-scope visible
//   grid.sync
//   phase 2: tile loop, software-pipelined (next tile's gc loads issued under MFMA+scatter)
__global__ __launch_bounds__(256, 3) void fused(
        const float* __restrict__ gc,
        const int*   __restrict__ idx,
        const float* __restrict__ Wc,
        const float* __restrict__ bias,
        int*         __restrict__ cnt,
        int*         __restrict__ pairs,
        float*       __restrict__ out) {
    __shared__ ushort Wl[NCLS * NCH];   // 32 KiB, B-fragment order, lives all kernel
    __shared__ ushort AO[64 * NCH];     // 16 KiB: A-frags, then fp16 prob transpose

    const int t    = threadIdx.x;
    const int lane = t & 63;
    const int wv   = t >> 6;
    const int l15  = lane & 15;
    const int quad = lane >> 4;
    const int nthr = (int)gridDim.x << 8;
    const int gtid = ((int)blockIdx.x << 8) + t;

    // ---- W: fp32 -> bf16 MFMA B-fragments, straight into LDS (once per block; Wc is L2-resident)
    //   Wl[((nt*4+kk)*64 + ln)*8 + j] = bf16( W[nt*16+(ln&15)][kk*32+(ln>>4)*8+j] )
    #pragma unroll
    for (int s = 0; s < 8; ++s) {
        int slot = (s << 8) + t;               // 0..2047
        int ln = slot & 63;
        int kk = (slot >> 6) & 3;
        int nt = slot >> 8;
        int n  = (nt << 4) + (ln & 15);
        int k0 = (kk << 5) + ((ln >> 4) << 3);
        const float* wp = Wc + n * NCH + k0;
        float4 w0 = *(const float4*)wp;
        float4 w1 = *(const float4*)(wp + 4);
        ushort u[8];
        u[0] = f2bf(w0.x); u[1] = f2bf(w0.y); u[2] = f2bf(w0.z); u[3] = f2bf(w0.w);
        u[4] = f2bf(w1.x); u[5] = f2bf(w1.y); u[6] = f2bf(w1.z); u[7] = f2bf(w1.w);
        *(bf16x8*)&Wl[slot << 3] = *(bf16x8*)u;
    }

    // ---- zero tile counters (grid-stride)
    for (int i = gtid; i < NTILE; i += nthr) cnt[i] = 0;

    // ---- prefetch first A-tile NOW: HBM streams while the grid syncs + does atomics
    float4 va[8];
    int tt = blockIdx.x;
    {
        const int m0 = tt << 6;
        #pragma unroll
        for (int i = 0; i < 4; ++i) {
            int q  = (i << 8) + t;
            int cp = q >> 4, mq = q & 15;
            int c0 = cp << 1, m = mq << 2;
            va[2 * i]     = *(const float4*)&gc[(size_t)c0 * HW + m0 + m];
            va[2 * i + 1] = *(const float4*)&gc[(size_t)(c0 + 1) * HW + m0 + m];
        }
    }

    cg::this_grid().sync();   // cnt zeroed everywhere

    // ---- bucket each output row k by its source tile p>>6; entry packs (k<<6)|(p&63)
    for (int k = gtid; k < KROWS; k += nthr) {
        int p = idx[k];
        int tile = p >> 6;
        int pos = atomicAdd(&cnt[tile], 1);
        if (pos < CAP) pairs[tile * CAP + pos] = (k << 6) | (p & 63);
    }
    __threadfence();

    cg::this_grid().sync();   // all buckets complete + visible device-wide

    float bcol[8];
    #pragma unroll
    for (int nt = 0; nt < 8; ++nt) bcol[nt] = bias[(nt << 4) + l15];

    const int stride = (int)gridDim.x;
    for (; tt < NTILE; tt += stride) {
        // ---- convert current tile -> A fragments, slot XOR-swizzled by (row>>2)&7
        #pragma unroll
        for (int i = 0; i < 4; ++i) {
            int q  = (i << 8) + t;
            int cp = q >> 4, mq = q & 15;
            int c0 = cp << 1, m = mq << 2;
            int kk = c0 >> 5, kc2 = (c0 >> 3) & 3, j = c0 & 7;
            const float* a0 = (const float*)&va[2 * i];
            const float* a1 = (const float*)&va[2 * i + 1];
            #pragma unroll
            for (int d = 0; d < 4; ++d) {
                int row  = m + d;
                int slot = ((((row >> 4) << 2) + kk) << 6) + (row & 15) + (kc2 << 4);
                slot ^= (row >> 2) & 7;
                __hip_bfloat162 pk = __float22bfloat162_rn(make_float2(a0[d], a1[d]));
                *(ushort2*)&AO[(slot << 3) + j] = *(ushort2*)&pk;
            }
        }
        __syncthreads();   // A ready (W resident since phase 0)

        // ---- issue next tile's global loads; latency hides under MFMA+softmax+scatter
        const int tn = tt + stride;
        float4 vb[8];
        if (tn < NTILE) {
            const int m1 = tn << 6;
            #pragma unroll
            for (int i = 0; i < 4; ++i) {
                int q  = (i << 8) + t;
                int cp = q >> 4, mq = q & 15;
                int c0 = cp << 1, m = mq << 2;
                vb[2 * i]     = *(const float4*)&gc[(size_t)c0 * HW + m1 + m];
                vb[2 * i + 1] = *(const float4*)&gc[(size_t)(c0 + 1) * HW + m1 + m];
            }
        }

        // ---- MFMA: wave wv owns 16 rows x 128 cols, K=128 in 4 steps
        f32x4 acc[8];
        #pragma unroll
        for (int i = 0; i < 8; ++i) acc[i] = (f32x4){0.f, 0.f, 0.f, 0.f};

        #pragma unroll
        for (int kk = 0; kk < 4; ++kk) {
            int aslot = ((((wv << 2) + kk) << 6) + lane) ^ ((((wv << 4) + l15) >> 2) & 7);
            bf16x8 a = *(const bf16x8*)&AO[aslot << 3];
            #pragma unroll
            for (int nt = 0; nt < 8; ++nt) {
                bf16x8 b = *(const bf16x8*)&Wl[((((nt << 2) + kk) << 6) + lane) << 3];
                acc[nt] = __builtin_amdgcn_mfma_f32_16x16x32_bf16(a, b, acc[nt], 0, 0, 0);
            }
        }

        // ---- softmax in place (C/D layout: col=l15+nt*16, row=quad*4+rr)
        float inv[4];
        #pragma unroll
        for (int rr = 0; rr < 4; ++rr) {
            float s = 0.f;
            #pragma unroll
            for (int nt = 0; nt < 8; ++nt) {
                acc[nt][rr] = __expf(acc[nt][rr] + bcol[nt]);
                s += acc[nt][rr];
            }
            s += __shfl_xor(s, 1, 64);
            s += __shfl_xor(s, 2, 64);
            s += __shfl_xor(s, 4, 64);
            s += __shfl_xor(s, 8, 64);
            inv[rr] = 1.0f / s;
        }

        // ---- transpose probs (fp16) into the wave's OWN A region
        const int g = ((quad & 1) << 2) | (quad & 2);
        #pragma unroll
        for (int nt = 0; nt < 8; ++nt) {
            int cl = ((nt << 1) + (l15 >> 3)) ^ g;
            #pragma unroll
            for (int rr = 0; rr < 4; ++rr) {
                int row = (wv << 4) + (quad << 2) + rr;
                AO[(row << 7) + (cl << 3) + (l15 & 7)] =
                    __half_as_ushort(__float2half_rn(acc[nt][rr] * inv[rr]));
            }
        }
        __syncthreads();   // all 64 rows' probs visible to all waves

        // ---- scatter: wave wv handles bucket entries e = wv, wv+4, ...
        const int nb = min(cnt[tt], CAP);
        const int* pb = pairs + tt * CAP;
        #pragma unroll 2
        for (int e = wv; e < nb; e += 4) {
            int pk  = pb[e];
            int row = pk & 63;
            int k   = pk >> 6;
            int qd  = (row >> 2) & 3;
            int gq  = ((qd & 1) << 2) | (qd & 2);
            int cl  = (lane >> 2) ^ gq;
            __half2 h = *(const __half2*)&AO[(row << 7) + (cl << 3) + ((lane << 1) & 7)];
            float2 f = __half22float2(h);
            *(float2*)&out[((size_t)k << 7) + (lane << 1)] = f;
        }
        __syncthreads();   // scatter done before next convert overwrites AO

        if (tn < NTILE) {
            #pragma unroll
            for (int i = 0; i < 8; ++i) va[i] = vb[i];
        }
    }
}

extern "C" void kernel_launch(void* const* d_in, const int* in_sizes, int n_in,
                              void* d_out, int out_size, void* d_ws, size_t ws_size,
                              hipStream_t stream) {
    const float* gc   = (const float*)d_in[0];   // [1,128,512,512] fp32
    const int*   idx  = (const int*)d_in[1];     // [1,131072] int32
    const float* Wc   = (const float*)d_in[2];   // [128,128] fp32
    const float* bias = (const float*)d_in[3];   // [128] fp32
    float* out = (float*)d_out;                  // [131072,128] fp32

    char* ws = (char*)d_ws;
    int* cnt   = (int*)(ws);                     // 4096 ints (16 KiB)
    int* pairs = (int*)(ws + 0x10000);           // 4096*192 ints (3 MiB)

    // size the cooperative grid to exactly-resident capacity (expect 3 blocks/CU x 256 CU = 768)
    static int nblk = 0;
    if (nblk == 0) {
        int occ = 0;
        if (hipOccupancyMaxActiveBlocksPerMultiprocessor(&occ, fused, 256, 0) != hipSuccess || occ < 1)
            occ = 1;
        if (occ > 16) occ = 16;
        int ncu = 256;
        hipDeviceProp_t prop;
        if (hipGetDeviceProperties(&prop, 0) == hipSuccess && prop.multiProcessorCount > 0)
            ncu = prop.multiProcessorCount;
        nblk = occ * ncu;
        if (nblk > NTILE) nblk = NTILE;
    }

    void* args[] = {(void*)&gc, (void*)&idx, (void*)&Wc, (void*)&bias,
                    (void*)&cnt, (void*)&pairs, (void*)&out};
    hipLaunchCooperativeKernel(fused, dim3(nblk), dim3(256), args, 0, stream);
}

// Round 4
// 239.542 us; speedup vs baseline: 1.4858x; 1.4858x over previous
//
#include <hip/hip_runtime.h>
#include <hip/hip_bf16.h>
#include <hip/hip_fp16.h>

#define HW      262144   // 512*512 spatial positions
#define NCH     128      // channels (GEMM K)
#define NCLS    128      // classes  (GEMM N)
#define KROWS   131072   // gathered rows
#define NTILE   4096     // HW / 64
#define CAP     192      // entries per tile bucket (Poisson mean 32; P(>192) ~ 0)
#define TPB     2        // tiles per block (depth-1 prefetch pipeline)

typedef short  bf16x8 __attribute__((ext_vector_type(8)));
typedef float  f32x4  __attribute__((ext_vector_type(4)));
typedef float  f32x2  __attribute__((ext_vector_type(2)));

__device__ inline ushort f2bf(float f) {
    union { float f; unsigned u; } v; v.f = f;
    unsigned u = v.u;
    return (ushort)((u + 0x7FFFu + ((u >> 16) & 1u)) >> 16);   // RNE
}

// bucket each output row k by its source tile p>>6; entry packs (k<<6)|(p&63)
__global__ __launch_bounds__(256) void csr_fill(const int* __restrict__ idx,
                                                int* __restrict__ cnt,
                                                int* __restrict__ pairs) {
    int k = blockIdx.x * 256 + threadIdx.x;
    int p = idx[k];
    int tile = p >> 6;
    int pos = atomicAdd(&cnt[tile], 1);
    if (pos < CAP) pairs[tile * CAP + pos] = (k << 6) | (p & 63);
}

// Each one-shot block: convert W once into LDS, then process TPB=2 tiles with
// depth-1 prefetch (tile p+1's gc loads issued under tile p's MFMA+softmax+scatter).
__global__ __launch_bounds__(256, 3) void gemm_scatter(const float* __restrict__ gc,
                                                       const float* __restrict__ Wc,
                                                       const float* __restrict__ bias,
                                                       const int* __restrict__ cnt,
                                                       const int* __restrict__ pairs,
                                                       float* __restrict__ out) {
    __shared__ ushort Wl[NCLS * NCH];   // 32 KiB, B-fragment order, lives across both tiles
    __shared__ ushort AO[64 * NCH];     // 16 KiB: A-frags, then fp16 prob transpose

    const int t    = threadIdx.x;
    const int lane = t & 63;
    const int wv   = t >> 6;
    const int l15  = lane & 15;
    const int quad = lane >> 4;
    const int t0   = blockIdx.x * TPB;

    // ---- issue tile-0 A loads first (longest latency: HBM)
    float4 va[8];
    {
        const int m0 = t0 << 6;
        #pragma unroll
        for (int i = 0; i < 4; ++i) {
            int q  = (i << 8) + t;
            int cp = q >> 4, mq = q & 15;
            int c0 = cp << 1, m = mq << 2;
            va[2 * i]     = *(const float4*)&gc[(size_t)c0 * HW + m0 + m];
            va[2 * i + 1] = *(const float4*)&gc[(size_t)(c0 + 1) * HW + m0 + m];
        }
    }

    // ---- W: fp32 -> bf16 MFMA B-fragments straight into LDS (Wc is L2-resident)
    //   Wl[((nt*4+kk)*64 + ln)*8 + j] = bf16( W[nt*16+(ln&15)][kk*32+(ln>>4)*8+j] )
    #pragma unroll
    for (int s = 0; s < 8; ++s) {
        int slot = (s << 8) + t;               // 0..2047
        int ln = slot & 63;
        int kk = (slot >> 6) & 3;
        int nt = slot >> 8;
        int n  = (nt << 4) + (ln & 15);
        int k0 = (kk << 5) + ((ln >> 4) << 3);
        const float* wp = Wc + n * NCH + k0;
        float4 w0 = *(const float4*)wp;
        float4 w1 = *(const float4*)(wp + 4);
        ushort u[8];
        u[0] = f2bf(w0.x); u[1] = f2bf(w0.y); u[2] = f2bf(w0.z); u[3] = f2bf(w0.w);
        u[4] = f2bf(w1.x); u[5] = f2bf(w1.y); u[6] = f2bf(w1.z); u[7] = f2bf(w1.w);
        *(bf16x8*)&Wl[slot << 3] = *(bf16x8*)u;
    }

    float bcol[8];
    #pragma unroll
    for (int nt = 0; nt < 8; ++nt) bcol[nt] = bias[(nt << 4) + l15];

    float4 vb[8];

    #pragma unroll
    for (int p = 0; p < TPB; ++p) {
        // ---- convert current tile -> A fragments, slot XOR-swizzled by (row>>2)&7
        #pragma unroll
        for (int i = 0; i < 4; ++i) {
            int q  = (i << 8) + t;
            int cp = q >> 4, mq = q & 15;
            int c0 = cp << 1, m = mq << 2;
            int kk = c0 >> 5, kc2 = (c0 >> 3) & 3, j = c0 & 7;
            const float* a0 = (const float*)&va[2 * i];
            const float* a1 = (const float*)&va[2 * i + 1];
            #pragma unroll
            for (int d = 0; d < 4; ++d) {
                int row  = m + d;
                int slot = ((((row >> 4) << 2) + kk) << 6) + (row & 15) + (kc2 << 4);
                slot ^= (row >> 2) & 7;
                __hip_bfloat162 pk = __float22bfloat162_rn(make_float2(a0[d], a1[d]));
                *(ushort2*)&AO[(slot << 3) + j] = *(ushort2*)&pk;
            }
        }
        __syncthreads();   // A (+W on first pass) ready

        // ---- issue next tile's gc loads; latency hides under MFMA+softmax+scatter
        if (p + 1 < TPB) {
            const int m1 = (t0 + p + 1) << 6;
            #pragma unroll
            for (int i = 0; i < 4; ++i) {
                int q  = (i << 8) + t;
                int cp = q >> 4, mq = q & 15;
                int c0 = cp << 1, m = mq << 2;
                vb[2 * i]     = *(const float4*)&gc[(size_t)c0 * HW + m1 + m];
                vb[2 * i + 1] = *(const float4*)&gc[(size_t)(c0 + 1) * HW + m1 + m];
            }
        }

        // ---- MFMA: wave wv owns 16 rows x 128 cols, K=128 in 4 steps
        f32x4 acc[8];
        #pragma unroll
        for (int i = 0; i < 8; ++i) acc[i] = (f32x4){0.f, 0.f, 0.f, 0.f};

        #pragma unroll
        for (int kk = 0; kk < 4; ++kk) {
            int aslot = ((((wv << 2) + kk) << 6) + lane) ^ ((((wv << 4) + l15) >> 2) & 7);
            bf16x8 a = *(const bf16x8*)&AO[aslot << 3];
            #pragma unroll
            for (int nt = 0; nt < 8; ++nt) {
                bf16x8 b = *(const bf16x8*)&Wl[((((nt << 2) + kk) << 6) + lane) << 3];
                acc[nt] = __builtin_amdgcn_mfma_f32_16x16x32_bf16(a, b, acc[nt], 0, 0, 0);
            }
        }

        // ---- softmax in place (C/D layout: col=l15+nt*16, row=quad*4+rr)
        float inv[4];
        #pragma unroll
        for (int rr = 0; rr < 4; ++rr) {
            float s = 0.f;
            #pragma unroll
            for (int nt = 0; nt < 8; ++nt) {
                acc[nt][rr] = __expf(acc[nt][rr] + bcol[nt]);
                s += acc[nt][rr];
            }
            s += __shfl_xor(s, 1, 64);
            s += __shfl_xor(s, 2, 64);
            s += __shfl_xor(s, 4, 64);
            s += __shfl_xor(s, 8, 64);
            inv[rr] = 1.0f / s;
        }

        // ---- transpose probs (fp16) into the wave's OWN A region
        const int g = ((quad & 1) << 2) | (quad & 2);
        #pragma unroll
        for (int nt = 0; nt < 8; ++nt) {
            int cl = ((nt << 1) + (l15 >> 3)) ^ g;
            #pragma unroll
            for (int rr = 0; rr < 4; ++rr) {
                int row = (wv << 4) + (quad << 2) + rr;
                AO[(row << 7) + (cl << 3) + (l15 & 7)] =
                    __half_as_ushort(__float2half_rn(acc[nt][rr] * inv[rr]));
            }
        }
        __syncthreads();   // all 64 rows' probs visible to all waves

        // ---- scatter: wave wv handles bucket entries e = wv, wv+4, ...
        const int tt = t0 + p;
        const int nb = min(cnt[tt], CAP);
        const int* pb = pairs + tt * CAP;
        #pragma unroll 2
        for (int e = wv; e < nb; e += 4) {
            int pk  = pb[e];
            int row = pk & 63;
            int k   = pk >> 6;
            int qd  = (row >> 2) & 3;
            int gq  = ((qd & 1) << 2) | (qd & 2);
            int cl  = (lane >> 2) ^ gq;
            __half2 h = *(const __half2*)&AO[(row << 7) + (cl << 3) + ((lane << 1) & 7)];
            float2 f = __half22float2(h);
            f32x2 fv; fv.x = f.x; fv.y = f.y;
            __builtin_nontemporal_store(fv, (f32x2*)&out[((size_t)k << 7) + (lane << 1)]);
        }

        if (p + 1 < TPB) {
            __syncthreads();   // scatter done before next convert overwrites AO
            #pragma unroll
            for (int i = 0; i < 8; ++i) va[i] = vb[i];
        }
    }
}

extern "C" void kernel_launch(void* const* d_in, const int* in_sizes, int n_in,
                              void* d_out, int out_size, void* d_ws, size_t ws_size,
                              hipStream_t stream) {
    const float* gc   = (const float*)d_in[0];   // [1,128,512,512] fp32
    const int*   idx  = (const int*)d_in[1];     // [1,131072] int32
    const float* Wc   = (const float*)d_in[2];   // [128,128] fp32
    const float* bias = (const float*)d_in[3];   // [128] fp32
    float* out = (float*)d_out;                  // [131072,128] fp32

    char* ws = (char*)d_ws;
    int* cnt   = (int*)(ws);                     // 4096 ints (16 KiB)
    int* pairs = (int*)(ws + 0x10000);           // 4096*192 ints (3 MiB)

    (void)hipMemsetAsync(cnt, 0, NTILE * sizeof(int), stream);
    csr_fill    <<<dim3(KROWS / 256), dim3(256), 0, stream>>>(idx, cnt, pairs);
    gemm_scatter<<<dim3(NTILE / TPB), dim3(256), 0, stream>>>(gc, Wc, bias, cnt, pairs, out);
}

// Round 6
// 238.833 us; speedup vs baseline: 1.4902x; 1.0030x over previous
//
#include <hip/hip_runtime.h>
#include <hip/hip_bf16.h>
#include <hip/hip_fp16.h>

#define HW      262144   // 512*512 spatial positions
#define NCH     128      // channels (GEMM K)
#define NCLS    128      // classes  (GEMM N)
#define KROWS   131072   // gathered rows
#define NTILE   4096     // HW / 64
#define TPB     2        // tiles per block (depth-1 prefetch pipeline)

typedef short  bf16x8 __attribute__((ext_vector_type(8)));
typedef float  f32x4  __attribute__((ext_vector_type(4)));

__device__ inline ushort f2bf(float f) {
    union { float f; unsigned u; } v; v.f = f;
    unsigned u = v.u;
    return (ushort)((u + 0x7FFFu + ((u >> 16) & 1u)) >> 16);   // RNE
}

// Dense GEMM+softmax over ALL spatial positions -> fp16 probs tmp[HW][128].
// No atomics, no buckets, all stores coalesced. W converted inline to LDS.
__global__ __launch_bounds__(256, 3) void gemm_probs(const float* __restrict__ gc,
                                                     const float* __restrict__ Wc,
                                                     const float* __restrict__ bias,
                                                     ushort* __restrict__ tmp) {
    __shared__ ushort Wl[NCLS * NCH];   // 32 KiB, B-fragment order, lives across both tiles
    __shared__ ushort AO[64 * NCH];     // 16 KiB: A-frags, then fp16 prob transpose

    const int t    = threadIdx.x;
    const int lane = t & 63;
    const int wv   = t >> 6;
    const int l15  = lane & 15;
    const int quad = lane >> 4;
    const int t0   = blockIdx.x * TPB;

    // ---- issue tile-0 A loads first (longest latency: HBM)
    float4 va[8];
    {
        const int m0 = t0 << 6;
        #pragma unroll
        for (int i = 0; i < 4; ++i) {
            int q  = (i << 8) + t;
            int cp = q >> 4, mq = q & 15;
            int c0 = cp << 1, m = mq << 2;
            va[2 * i]     = *(const float4*)&gc[(size_t)c0 * HW + m0 + m];
            va[2 * i + 1] = *(const float4*)&gc[(size_t)(c0 + 1) * HW + m0 + m];
        }
    }

    // ---- W: fp32 -> bf16 MFMA B-fragments straight into LDS (Wc is L2-resident)
    //   Wl[((nt*4+kk)*64 + ln)*8 + j] = bf16( W[nt*16+(ln&15)][kk*32+(ln>>4)*8+j] )
    #pragma unroll
    for (int s = 0; s < 8; ++s) {
        int slot = (s << 8) + t;               // 0..2047
        int ln = slot & 63;
        int kk = (slot >> 6) & 3;
        int nt = slot >> 8;
        int n  = (nt << 4) + (ln & 15);
        int k0 = (kk << 5) + ((ln >> 4) << 3);
        const float* wp = Wc + n * NCH + k0;
        float4 w0 = *(const float4*)wp;
        float4 w1 = *(const float4*)(wp + 4);
        ushort u[8];
        u[0] = f2bf(w0.x); u[1] = f2bf(w0.y); u[2] = f2bf(w0.z); u[3] = f2bf(w0.w);
        u[4] = f2bf(w1.x); u[5] = f2bf(w1.y); u[6] = f2bf(w1.z); u[7] = f2bf(w1.w);
        *(bf16x8*)&Wl[slot << 3] = *(bf16x8*)u;
    }

    float bcol[8];
    #pragma unroll
    for (int nt = 0; nt < 8; ++nt) bcol[nt] = bias[(nt << 4) + l15];

    float4 vb[8];

    #pragma unroll
    for (int p = 0; p < TPB; ++p) {
        // ---- convert current tile -> A fragments, slot XOR-swizzled by (row>>2)&7
        #pragma unroll
        for (int i = 0; i < 4; ++i) {
            int q  = (i << 8) + t;
            int cp = q >> 4, mq = q & 15;
            int c0 = cp << 1, m = mq << 2;
            int kk = c0 >> 5, kc2 = (c0 >> 3) & 3, j = c0 & 7;
            const float* a0 = (const float*)&va[2 * i];
            const float* a1 = (const float*)&va[2 * i + 1];
            #pragma unroll
            for (int d = 0; d < 4; ++d) {
                int row  = m + d;
                int slot = ((((row >> 4) << 2) + kk) << 6) + (row & 15) + (kc2 << 4);
                slot ^= (row >> 2) & 7;
                __hip_bfloat162 pk = __float22bfloat162_rn(make_float2(a0[d], a1[d]));
                *(ushort2*)&AO[(slot << 3) + j] = *(ushort2*)&pk;
            }
        }
        __syncthreads();   // A (+W on first pass) ready

        // ---- issue next tile's gc loads; latency hides under MFMA+softmax+store
        if (p + 1 < TPB) {
            const int m1 = (t0 + p + 1) << 6;
            #pragma unroll
            for (int i = 0; i < 4; ++i) {
                int q  = (i << 8) + t;
                int cp = q >> 4, mq = q & 15;
                int c0 = cp << 1, m = mq << 2;
                vb[2 * i]     = *(const float4*)&gc[(size_t)c0 * HW + m1 + m];
                vb[2 * i + 1] = *(const float4*)&gc[(size_t)(c0 + 1) * HW + m1 + m];
            }
        }

        // ---- MFMA: wave wv owns 16 rows x 128 cols, K=128 in 4 steps
        f32x4 acc[8];
        #pragma unroll
        for (int i = 0; i < 8; ++i) acc[i] = (f32x4){0.f, 0.f, 0.f, 0.f};

        #pragma unroll
        for (int kk = 0; kk < 4; ++kk) {
            int aslot = ((((wv << 2) + kk) << 6) + lane) ^ ((((wv << 4) + l15) >> 2) & 7);
            bf16x8 a = *(const bf16x8*)&AO[aslot << 3];
            #pragma unroll
            for (int nt = 0; nt < 8; ++nt) {
                bf16x8 b = *(const bf16x8*)&Wl[((((nt << 2) + kk) << 6) + lane) << 3];
                acc[nt] = __builtin_amdgcn_mfma_f32_16x16x32_bf16(a, b, acc[nt], 0, 0, 0);
            }
        }

        // ---- softmax in place (C/D layout: col=l15+nt*16, row=quad*4+rr)
        float inv[4];
        #pragma unroll
        for (int rr = 0; rr < 4; ++rr) {
            float s = 0.f;
            #pragma unroll
            for (int nt = 0; nt < 8; ++nt) {
                acc[nt][rr] = __expf(acc[nt][rr] + bcol[nt]);
                s += acc[nt][rr];
            }
            s += __shfl_xor(s, 1, 64);
            s += __shfl_xor(s, 2, 64);
            s += __shfl_xor(s, 4, 64);
            s += __shfl_xor(s, 8, 64);
            inv[rr] = 1.0f / s;
        }

        // ---- transpose probs (fp16) into the wave's OWN A region
        // chunk swizzle g(quad) = ((quad&1)<<2)|(quad&2); stored chunk = logical ^ g
        const int g = ((quad & 1) << 2) | (quad & 2);
        #pragma unroll
        for (int nt = 0; nt < 8; ++nt) {
            int cl = ((nt << 1) + (l15 >> 3)) ^ g;
            #pragma unroll
            for (int rr = 0; rr < 4; ++rr) {
                int row = (wv << 4) + (quad << 2) + rr;
                AO[(row << 7) + (cl << 3) + (l15 & 7)] =
                    __half_as_ushort(__float2half_rn(acc[nt][rr] * inv[rr]));
            }
        }
        __syncthreads();   // all 64 rows' probs visible

        // ---- coalesced fp16 row store: 2 rows per iteration, 8 B per lane
        // lane covers cols c..c+3 of row (wv*16 + 2*r2 + lane/32), c = (lane&31)*4
        const int m0 = (t0 + p) << 6;
        const int c  = (lane & 31) << 2;
        const int rh = lane >> 5;
        #pragma unroll
        for (int r2 = 0; r2 < 8; ++r2) {
            int row = (wv << 4) + (r2 << 1) + rh;
            int qd  = (row >> 2) & 3;
            int gq  = ((qd & 1) << 2) | (qd & 2);
            int ch  = (c >> 3) ^ gq;
            uint2 u = *(const uint2*)&AO[(row << 7) + (ch << 3) + (c & 7)];
            *(uint2*)&tmp[((size_t)(m0 + row) << 7) + c] = u;
        }

        if (p + 1 < TPB) {
            __syncthreads();   // stores read AO before next convert overwrites it
            #pragma unroll
            for (int i = 0; i < 8; ++i) va[i] = vb[i];
        }
    }
}

// out[r][:] = fp32(tmp[idx[r]][:]) — random 256 B reads (L3-resident tmp),
// fully coalesced float4 NT writes. 16 rows per wave, 64 rows per block.
__global__ __launch_bounds__(256) void gather_rows(const int* __restrict__ idx,
                                                   const ushort* __restrict__ tmp,
                                                   float* __restrict__ out) {
    const int lane = threadIdx.x & 63;
    const int wv   = threadIdx.x >> 6;
    const int base = (blockIdx.x * 4 + wv) * 16;
    const int rh   = lane >> 5;        // half-wave handles one row
    const int l31  = lane & 31;
    #pragma unroll 2
    for (int i = 0; i < 8; ++i) {
        int r = base + (i << 1) + rh;
        int k = idx[r];
        uint2 u = *(const uint2*)&tmp[((size_t)k << 7) + (l31 << 2)];
        __half2 h0 = *(__half2*)&u.x;
        __half2 h1 = *(__half2*)&u.y;
        float2 f0 = __half22float2(h0);
        float2 f1 = __half22float2(h1);
        f32x4 fv; fv.x = f0.x; fv.y = f0.y; fv.z = f1.x; fv.w = f1.y;
        __builtin_nontemporal_store(fv, (f32x4*)&out[((size_t)r << 7) + (l31 << 2)]);
    }
}

extern "C" void kernel_launch(void* const* d_in, const int* in_sizes, int n_in,
                              void* d_out, int out_size, void* d_ws, size_t ws_size,
                              hipStream_t stream) {
    const float* gc   = (const float*)d_in[0];   // [1,128,512,512] fp32
    const int*   idx  = (const int*)d_in[1];     // [1,131072] int32
    const float* Wc   = (const float*)d_in[2];   // [128,128] fp32
    const float* bias = (const float*)d_in[3];   // [128] fp32
    float* out = (float*)d_out;                  // [131072,128] fp32

    ushort* tmp = (ushort*)d_ws;                 // [HW][128] fp16 probs (64 MiB)

    gemm_probs <<<dim3(NTILE / TPB), dim3(256), 0, stream>>>(gc, Wc, bias, tmp);
    gather_rows<<<dim3(KROWS / 64),  dim3(256), 0, stream>>>(idx, tmp, out);
}